// Round 16
// baseline (550.075 us; speedup 1.0000x reference)
//
#include <hip/hip_runtime.h>
#include <cstdint>

#define B_   8
#define CIN  64
#define DIM_ 256
#define H_   128
#define W_   128
#define HW_  (H_*W_)

typedef unsigned short u16;
typedef unsigned int   u32;
typedef short short8 __attribute__((ext_vector_type(8)));
typedef float f32x4  __attribute__((ext_vector_type(4)));

__device__ __forceinline__ u16 f2bf(float f) {
    u32 u = __float_as_uint(f);
    u32 r = (u + 0x7fffu + ((u >> 16) & 1u)) >> 16;
    return (u16)r;
}
__device__ __forceinline__ float bf2f(u16 h) {
    return __uint_as_float(((u32)h) << 16);
}

// ---------------------------------------------------------------------------
// convdw v4 (banked at ~45us/tensor): FUSED conv1x1 + depthwise3x3.
// Tile 16x8 output (10x18 halo), LDS 45.8 KB, grid (128 tiles, 8 b), 512 thr.
// ---------------------------------------------------------------------------
__global__ __launch_bounds__(512, 6) void convdw_kernel(
    const float* __restrict__ in, const float* __restrict__ Wc,
    const float* __restrict__ Wd, u16* __restrict__ dst)
{
    __shared__ u16 Wtc[2][32 * 64];
    __shared__ u16 Xt[192 * 64];
    __shared__ u16 Pt[32 * 196];
    __shared__ float wlds[9 * 36];

    const int tid = threadIdx.x;
    const int tile = blockIdx.x;
    const int b = blockIdx.y;
    const int y0 = (tile >> 3) * 8;
    const int x0 = (tile & 7) * 16;

    {
        const int row = tid >> 4, seg = tid & 15;
        float4 f = *(const float4*)(Wc + (size_t)row * 64 + seg * 4);
        uint2 pk;
        pk.x = f2bf(f.x) | ((u32)f2bf(f.y) << 16);
        pk.y = f2bf(f.z) | ((u32)f2bf(f.w) << 16);
        *(uint2*)&Wtc[0][row * 64 + ((seg * 4) ^ ((row & 7) << 3))] = pk;
    }
    {
        const float* inb = in + (size_t)b * CIN * HW_;
        for (int i = tid; i < 1440; i += 512) {
            int chg = i / 180;
            int px = i - chg * 180;
            int py = px / 18;
            int pxi = px - py * 18;
            int gy = y0 - 1 + py, gx = x0 - 1 + pxi;
            uint4 pk = make_uint4(0, 0, 0, 0);
            if (gy >= 0 && gy < H_ && gx >= 0 && gx < W_) {
                const float* sp = inb + (size_t)(chg * 8) * HW_ + (size_t)gy * W_ + gx;
                u32 wv[4];
                #pragma unroll
                for (int j = 0; j < 4; ++j) {
                    float a = sp[(size_t)(2 * j) * HW_];
                    float c = sp[(size_t)(2 * j + 1) * HW_];
                    wv[j] = f2bf(a) | ((u32)f2bf(c) << 16);
                }
                pk = make_uint4(wv[0], wv[1], wv[2], wv[3]);
            }
            *(uint4*)&Xt[px * 64 + ((chg * 8) ^ ((px & 7) << 3))] = pk;
        }
    }
    __syncthreads();

    const int lane = tid & 63, w = tid >> 6;
    const int g = lane >> 4, ln = lane & 15;
    const int wm = w & 1;
    const int wpar = w >> 1;

    u16* db = dst + (size_t)b * DIM_ * HW_;

    for (int c = 0; c < 8; ++c) {
        const int cb = c & 1;
        f32x4 acc[3];
        #pragma unroll
        for (int jj = 0; jj < 3; ++jj) acc[jj] = (f32x4){0.f, 0.f, 0.f, 0.f};
        short8 af[2];
        {
            int m = wm * 16 + ln;
            af[0] = *(const short8*)&Wtc[cb][m * 64 + ((g * 8) ^ ((m & 7) << 3))];
            af[1] = *(const short8*)&Wtc[cb][m * 64 + ((32 + g * 8) ^ ((m & 7) << 3))];
        }
        #pragma unroll
        for (int jj = 0; jj < 3; ++jj) {
            int j = jj * 4 + wpar;
            int px = j * 16 + ln;
            #pragma unroll
            for (int ks = 0; ks < 2; ++ks) {
                short8 bf = *(const short8*)&Xt[px * 64 + ((ks * 32 + g * 8) ^ ((px & 7) << 3))];
                acc[jj] = __builtin_amdgcn_mfma_f32_16x16x32_bf16(af[ks], bf, acc[jj], 0, 0, 0);
            }
        }

        if (c < 7) {
            const int row = tid >> 4, seg = tid & 15;
            float4 f = *(const float4*)(Wc + (size_t)((c + 1) * 32 + row) * 64 + seg * 4);
            uint2 pk;
            pk.x = f2bf(f.x) | ((u32)f2bf(f.y) << 16);
            pk.y = f2bf(f.z) | ((u32)f2bf(f.w) << 16);
            *(uint2*)&Wtc[cb ^ 1][row * 64 + ((seg * 4) ^ ((row & 7) << 3))] = pk;
        }

        #pragma unroll
        for (int jj = 0; jj < 3; ++jj) {
            int j = jj * 4 + wpar;
            int px = j * 16 + ln;
            #pragma unroll
            for (int r = 0; r < 4; ++r)
                Pt[(wm * 16 + g * 4 + r) * 196 + px] = f2bf(acc[jj][r]);
        }
        for (int i = tid; i < 288; i += 512) {
            int ch = i / 9, tap = i - ch * 9;
            wlds[tap * 36 + ch] = Wd[(size_t)(c * 32 + ch) * 9 + tap];
        }
        __syncthreads();

        {
            const int chl = tid >> 4;
            const int sub = tid & 15;
            const int oy = sub >> 1, ox0 = (sub & 1) * 8;
            float wr[9];
            #pragma unroll
            for (int t = 0; t < 9; ++t) wr[t] = wlds[t * 36 + chl];
            const u32* pw = (const u32*)&Pt[chl * 196];
            float R[3][10];
            #pragma unroll
            for (int dy = 0; dy < 3; ++dy) {
                int wbase = (oy + dy) * 9 + (ox0 >> 1);
                #pragma unroll
                for (int u = 0; u < 5; ++u) {
                    u32 wrd = pw[wbase + u];
                    R[dy][2 * u]     = bf2f((u16)wrd);
                    R[dy][2 * u + 1] = bf2f((u16)(wrd >> 16));
                }
            }
            float o[8];
            #pragma unroll
            for (int i = 0; i < 8; ++i) {
                float s = R[0][i] * wr[0];
                s = fmaf(R[0][i + 1], wr[1], s);
                s = fmaf(R[0][i + 2], wr[2], s);
                s = fmaf(R[1][i],     wr[3], s);
                s = fmaf(R[1][i + 1], wr[4], s);
                s = fmaf(R[1][i + 2], wr[5], s);
                s = fmaf(R[2][i],     wr[6], s);
                s = fmaf(R[2][i + 1], wr[7], s);
                s = fmaf(R[2][i + 2], wr[8], s);
                o[i] = s;
            }
            uint4 pk;
            pk.x = f2bf(o[0]) | ((u32)f2bf(o[1]) << 16);
            pk.y = f2bf(o[2]) | ((u32)f2bf(o[3]) << 16);
            pk.z = f2bf(o[4]) | ((u32)f2bf(o[5]) << 16);
            pk.w = f2bf(o[6]) | ((u32)f2bf(o[7]) << 16);
            *(uint4*)(db + (size_t)(c * 32 + chl) * HW_ + (size_t)(y0 + oy) * W_ + x0 + ox0) = pk;
        }
        if (c < 7) __syncthreads();
    }
}

// ---------------------------------------------------------------------------
// Gram via MFMA (verified): direct global fragments, sumsq = diagonals
// ---------------------------------------------------------------------------
__global__ __launch_bounds__(256) void gram_mfma_kernel(
    const u16* __restrict__ q, const u16* __restrict__ k,
    float* __restrict__ pgram, float* __restrict__ pssq, float* __restrict__ pssk)
{
    __shared__ float red[4][1024];
    __shared__ float redq[4][32];
    __shared__ float redk[4][32];

    const int bh = blockIdx.y;
    const int chunk = blockIdx.x;
    const int tid = threadIdx.x;
    const int lane = tid & 63, wid = tid >> 6;
    const int g = lane >> 4, ln = lane & 15;

    const size_t off = (size_t)(bh * 32 + ln) * HW_ + chunk * 2048 + wid * 512 + g * 8;
    const u16* qp = q + off;
    const u16* kp = k + off;

    f32x4 aqk[2][2] = {};
    f32x4 aqq[2] = {};
    f32x4 akk[2] = {};

    #pragma unroll 4
    for (int n = 0; n < 512; n += 32) {
        short8 qf[2], kf[2];
        qf[0] = *(const short8*)(qp + n);
        qf[1] = *(const short8*)(qp + (size_t)16 * HW_ + n);
        kf[0] = *(const short8*)(kp + n);
        kf[1] = *(const short8*)(kp + (size_t)16 * HW_ + n);
        #pragma unroll
        for (int ti = 0; ti < 2; ++ti)
            #pragma unroll
            for (int tj = 0; tj < 2; ++tj)
                aqk[ti][tj] = __builtin_amdgcn_mfma_f32_16x16x32_bf16(qf[ti], kf[tj], aqk[ti][tj], 0, 0, 0);
        #pragma unroll
        for (int ti = 0; ti < 2; ++ti) {
            aqq[ti] = __builtin_amdgcn_mfma_f32_16x16x32_bf16(qf[ti], qf[ti], aqq[ti], 0, 0, 0);
            akk[ti] = __builtin_amdgcn_mfma_f32_16x16x32_bf16(kf[ti], kf[ti], akk[ti], 0, 0, 0);
        }
    }

    #pragma unroll
    for (int ti = 0; ti < 2; ++ti)
        #pragma unroll
        for (int tj = 0; tj < 2; ++tj)
            #pragma unroll
            for (int r = 0; r < 4; ++r)
                red[wid][(ti * 16 + g * 4 + r) * 32 + tj * 16 + ln] = aqk[ti][tj][r];
    if ((ln >> 2) == g) {
        #pragma unroll
        for (int ti = 0; ti < 2; ++ti) {
            redq[wid][ti * 16 + ln] = aqq[ti][ln & 3];
            redk[wid][ti * 16 + ln] = akk[ti][ln & 3];
        }
    }
    __syncthreads();

    for (int p = tid; p < 1024; p += 256) {
        float s = red[0][p] + red[1][p] + red[2][p] + red[3][p];
        pgram[((size_t)bh * 8 + chunk) * 1024 + p] = s;
    }
    if (tid < 32) {
        pssq[((size_t)bh * 8 + chunk) * 32 + tid] =
            redq[0][tid] + redq[1][tid] + redq[2][tid] + redq[3][tid];
    } else if (tid < 64) {
        int j = tid & 31;
        pssk[((size_t)bh * 8 + chunk) * 32 + j] =
            redk[0][j] + redk[1][j] + redk[2][j] + redk[3][j];
    }
}

// ---------------------------------------------------------------------------
// reduce partials -> normalize -> softmax -> Amm(bf16) = Wproj_h @ attn
// ---------------------------------------------------------------------------
__global__ __launch_bounds__(256) void softproj_kernel(
    const float* __restrict__ pgram, const float* __restrict__ pssq,
    const float* __restrict__ pssk, const float* __restrict__ Wproj,
    const float* __restrict__ temp, u16* __restrict__ Amm)
{
    __shared__ float att[32][33];
    __shared__ float nq[32], nk[32];

    const int bh = blockIdx.x;
    const int h = bh & 7;
    const int b = bh >> 3;
    const int tid = threadIdx.x;

    for (int p = tid; p < 1024; p += 256) {
        float s = 0.f;
        #pragma unroll
        for (int c = 0; c < 8; ++c) s += pgram[((size_t)bh * 8 + c) * 1024 + p];
        att[p >> 5][p & 31] = s;
    }
    if (tid < 32) {
        float s = 0.f;
        #pragma unroll
        for (int c = 0; c < 8; ++c) s += pssq[((size_t)bh * 8 + c) * 32 + tid];
        nq[tid] = fmaxf(sqrtf(s), 1e-12f);
    } else if (tid < 64) {
        int i = tid & 31;
        float s = 0.f;
        #pragma unroll
        for (int c = 0; c < 8; ++c) s += pssk[((size_t)bh * 8 + c) * 32 + i];
        nk[i] = fmaxf(sqrtf(s), 1e-12f);
    }
    __syncthreads();

    const float T = temp[h];
    if (tid < 32) {
        int i = tid;
        float row[32];
        float mx = -1e30f;
        float qi = T / nq[i];
        #pragma unroll
        for (int j = 0; j < 32; ++j) {
            float v = att[i][j] * qi / nk[j];
            row[j] = v;
            mx = fmaxf(mx, v);
        }
        float s = 0.f;
        #pragma unroll
        for (int j = 0; j < 32; ++j) { float e = expf(row[j] - mx); row[j] = e; s += e; }
        float inv = 1.f / s;
        #pragma unroll
        for (int j = 0; j < 32; ++j) att[i][j] = row[j] * inv;
    }
    __syncthreads();

    const int o = tid;
    float wp[32];
    #pragma unroll
    for (int i2 = 0; i2 < 32; i2 += 4)
        *(float4*)&wp[i2] = *(const float4*)&Wproj[(size_t)o * DIM_ + h * 32 + i2];
    u16* arow = Amm + ((size_t)b * DIM_ + o) * DIM_ + h * 32;
    #pragma unroll
    for (int j = 0; j < 32; ++j) {
        float s = 0.f;
        #pragma unroll
        for (int i = 0; i < 32; ++i) s = fmaf(wp[i], att[i][j], s);
        arow[j] = f2bf(s);
    }
}

// ---------------------------------------------------------------------------
// cast Wfus [256][192] fp32 -> bf16 (once)
// ---------------------------------------------------------------------------
__global__ __launch_bounds__(256) void wfus_cast_kernel(
    const float* __restrict__ Wfus, u16* __restrict__ Afus)
{
    int idx = blockIdx.x * 256 + threadIdx.x;
    int base = idx * 8;
    float4 f0 = *(const float4*)(Wfus + base);
    float4 f1 = *(const float4*)(Wfus + base + 4);
    uint4 pk;
    pk.x = f2bf(f0.x) | ((u32)f2bf(f0.y) << 16);
    pk.y = f2bf(f0.z) | ((u32)f2bf(f0.w) << 16);
    pk.z = f2bf(f1.x) | ((u32)f2bf(f1.y) << 16);
    pk.w = f2bf(f1.z) | ((u32)f2bf(f1.w) << 16);
    *(uint4*)(Afus + base) = pk;
}

// ---------------------------------------------------------------------------
// final8: WAVE-LEVEL o-merge of final4. Block 512 = 8 waves; waves 0-3 ->
// o-group 0, waves 4-7 -> o-group 1. B staged ONCE per px-panel; per-thread
// regs identical to final4 (VGPR ~64) -> up to 4 blocks/CU = 32 waves.
// grid (128 px-panels, 8 b).
// ---------------------------------------------------------------------------
#define LOADB_F8(KC, W) do {                                                    \
    if ((KC) < 4) {                                                             \
        const u16* vb_ = vbuf + ((size_t)b * DIM_ + (KC) * 64 + qq * 16) * HW_ + px0 + pxu; \
        _Pragma("unroll") for (int jj_ = 0; jj_ < 8; ++jj_)                     \
            W[jj_] = (u32)vb_[(size_t)(2 * jj_) * HW_]                          \
                   | ((u32)vb_[(size_t)(2 * jj_ + 1) * HW_] << 16);             \
    } else {                                                                    \
        const float* bp_ = ((KC) == 4) ? xin : ((KC) == 5) ? yin : zin;         \
        const float* sp_ = bp_ + ((size_t)b * CIN + qq * 16) * HW_ + px0 + pxu; \
        _Pragma("unroll") for (int jj_ = 0; jj_ < 8; ++jj_)                     \
            W[jj_] = (u32)f2bf(sp_[(size_t)(2 * jj_) * HW_])                    \
                   | ((u32)f2bf(sp_[(size_t)(2 * jj_ + 1) * HW_]) << 16);       \
    } } while (0)

#define WRITEB_F8(BUF, W) do {                                                  \
    u16* dd_ = &Bl[BUF][pxu * 64];                                              \
    *(uint4*)&dd_[(qq * 16)     ^ ((pxu & 7) << 3)] = make_uint4(W[0], W[1], W[2], W[3]); \
    *(uint4*)&dd_[(qq * 16 + 8) ^ ((pxu & 7) << 3)] = make_uint4(W[4], W[5], W[6], W[7]); \
    } while (0)

#define LOADA_F8(KC, A) do {                                                    \
    _Pragma("unroll") for (int ks_ = 0; ks_ < 2; ++ks_)                         \
    _Pragma("unroll") for (int fm_ = 0; fm_ < 2; ++fm_) {                       \
        int m_ = m0 + fm_ * 16 + ln;                                            \
        const u16* ap_ = ((KC) < 4)                                             \
            ? Amm + ((size_t)b * DIM_ + m_) * DIM_ + (KC) * 64 + ks_ * 32 + g * 8 \
            : Afus + (size_t)m_ * 192 + ((KC) - 4) * 64 + ks_ * 32 + g * 8;     \
        A[ks_ * 2 + fm_] = *(const short8*)ap_;                                 \
    } } while (0)

__global__ __launch_bounds__(512, 6) void final8_kernel(
    const u16* __restrict__ Amm, const u16* __restrict__ Afus,
    const u16* __restrict__ vbuf,
    const float* __restrict__ xin, const float* __restrict__ yin,
    const float* __restrict__ zin, float* __restrict__ out)
{
    __shared__ u16 Bl[2][128 * 64];

    const int tid = threadIdx.x;
    const int px0 = blockIdx.x * 128;
    const int b   = blockIdx.y;
    const int lane = tid & 63, wid = tid >> 6;
    const int g = lane >> 4, ln = lane & 15;
    const int m0 = (wid >> 2) * 128 + (wid & 3) * 32;   // waves 0-3: o 0..127; 4-7: 128..255
    const int pxu = tid & 127;
    const int qq  = tid >> 7;      // 0..3 -> k-row group of 16

    f32x4 acc[2][8] = {};
    short8 aC[4], aN[4];
    u32 wN[8];

    LOADA_F8(0, aC);
    {
        u32 w0[8];
        LOADB_F8(0, w0);
        WRITEB_F8(0, w0);
    }
    __syncthreads();
    LOADA_F8(1, aN);
    LOADB_F8(1, wN);

    #pragma unroll
    for (int kc = 0; kc < 7; ++kc) {
        const int cur = kc & 1;

        #pragma unroll
        for (int ks = 0; ks < 2; ++ks)
            #pragma unroll
            for (int fn = 0; fn < 8; ++fn) {
                int p = fn * 16 + ln;
                short8 bf = *(const short8*)&Bl[cur][p * 64 + ((ks * 32 + g * 8) ^ ((p & 7) << 3))];
                acc[0][fn] = __builtin_amdgcn_mfma_f32_16x16x32_bf16(aC[ks * 2 + 0], bf, acc[0][fn], 0, 0, 0);
                acc[1][fn] = __builtin_amdgcn_mfma_f32_16x16x32_bf16(aC[ks * 2 + 1], bf, acc[1][fn], 0, 0, 0);
            }

        if (kc < 6) {
            WRITEB_F8(cur ^ 1, wN);
            __syncthreads();
            #pragma unroll
            for (int r = 0; r < 4; ++r) aC[r] = aN[r];
            if (kc < 5) {
                LOADA_F8(kc + 2, aN);
                LOADB_F8(kc + 2, wN);
            }
        }
    }

    float* op = out + (size_t)b * DIM_ * HW_;
    #pragma unroll
    for (int fm = 0; fm < 2; ++fm)
        #pragma unroll
        for (int fn = 0; fn < 8; ++fn)
            #pragma unroll
            for (int r = 0; r < 4; ++r) {
                int ch = m0 + fm * 16 + g * 4 + r;
                op[(size_t)ch * HW_ + px0 + fn * 16 + ln] = acc[fm][fn][r];
            }
}

// ---------------------------------------------------------------------------
extern "C" void kernel_launch(void* const* d_in, const int* in_sizes, int n_in,
                              void* d_out, int out_size, void* d_ws, size_t ws_size,
                              hipStream_t stream) {
    (void)in_sizes; (void)n_in; (void)out_size; (void)ws_size;

    const float* x     = (const float*)d_in[0];
    const float* y     = (const float*)d_in[1];
    const float* z     = (const float*)d_in[2];
    const float* Wq    = (const float*)d_in[3];
    const float* Wqd   = (const float*)d_in[4];
    const float* Wk    = (const float*)d_in[5];
    const float* Wkd   = (const float*)d_in[6];
    const float* Wv    = (const float*)d_in[7];
    const float* Wvd   = (const float*)d_in[8];
    const float* Wproj = (const float*)d_in[9];
    const float* Wfus  = (const float*)d_in[10];
    const float* temp  = (const float*)d_in[11];

    const size_t QELEMS = (size_t)B_ * DIM_ * HW_;   // 33.5M elems, 64 MiB bf16

    u16* qbuf = (u16*)d_out + QELEMS;         // q, dead after gram
    u16* kvbuf = (u16*)d_ws;                  // k, then v
    char* wsp = (char*)d_ws + QELEMS * sizeof(u16);
    float* pgram = (float*)wsp;                       wsp += 64 * 8 * 1024 * 4;
    float* pssq  = (float*)wsp;                       wsp += 64 * 8 * 32 * 4;
    float* pssk  = (float*)wsp;                       wsp += 64 * 8 * 32 * 4;
    u16*   Amm   = (u16*)wsp;                         wsp += (size_t)B_ * DIM_ * DIM_ * 2;
    u16*   Afus  = (u16*)wsp;

    dim3 fgrid(128, B_);

    wfus_cast_kernel<<<24, 256, 0, stream>>>(Wfus, Afus);
    convdw_kernel<<<fgrid, 512, 0, stream>>>(x, Wq, Wqd, qbuf);
    convdw_kernel<<<fgrid, 512, 0, stream>>>(y, Wk, Wkd, kvbuf);
    gram_mfma_kernel<<<dim3(8, 64), 256, 0, stream>>>(qbuf, kvbuf, pgram, pssq, pssk);
    softproj_kernel<<<64, 256, 0, stream>>>(pgram, pssq, pssk, Wproj, temp, Amm);
    convdw_kernel<<<fgrid, 512, 0, stream>>>(z, Wv, Wvd, kvbuf);
    final8_kernel<<<dim3(128, B_), 512, 0, stream>>>(Amm, Afus, kvbuf, x, y, z, (float*)d_out);
}

// Round 17
// 267.475 us; speedup vs baseline: 2.0565x; 2.0565x over previous
//
#include <hip/hip_runtime.h>
#include <cstdint>

#define B_   8
#define CIN  64
#define DIM_ 256
#define H_   128
#define W_   128
#define HW_  (H_*W_)

typedef unsigned short u16;
typedef unsigned int   u32;
typedef short short8 __attribute__((ext_vector_type(8)));
typedef float f32x4  __attribute__((ext_vector_type(4)));

__device__ __forceinline__ u16 f2bf(float f) {
    u32 u = __float_as_uint(f);
    u32 r = (u + 0x7fffu + ((u >> 16) & 1u)) >> 16;
    return (u16)r;
}
__device__ __forceinline__ float bf2f(u16 h) {
    return __uint_as_float(((u32)h) << 16);
}

// ---------------------------------------------------------------------------
// convdw v4 (banked ~45us/tensor): FUSED conv1x1 + depthwise3x3.
// Tile 16x8 output (10x18 halo), LDS 45.8 KB, grid (128 tiles, 8 b), 512 thr.
// ---------------------------------------------------------------------------
__global__ __launch_bounds__(512, 6) void convdw_kernel(
    const float* __restrict__ in, const float* __restrict__ Wc,
    const float* __restrict__ Wd, u16* __restrict__ dst)
{
    __shared__ u16 Wtc[2][32 * 64];
    __shared__ u16 Xt[192 * 64];
    __shared__ u16 Pt[32 * 196];
    __shared__ float wlds[9 * 36];

    const int tid = threadIdx.x;
    const int tile = blockIdx.x;
    const int b = blockIdx.y;
    const int y0 = (tile >> 3) * 8;
    const int x0 = (tile & 7) * 16;

    {
        const int row = tid >> 4, seg = tid & 15;
        float4 f = *(const float4*)(Wc + (size_t)row * 64 + seg * 4);
        uint2 pk;
        pk.x = f2bf(f.x) | ((u32)f2bf(f.y) << 16);
        pk.y = f2bf(f.z) | ((u32)f2bf(f.w) << 16);
        *(uint2*)&Wtc[0][row * 64 + ((seg * 4) ^ ((row & 7) << 3))] = pk;
    }
    {
        const float* inb = in + (size_t)b * CIN * HW_;
        for (int i = tid; i < 1440; i += 512) {
            int chg = i / 180;
            int px = i - chg * 180;
            int py = px / 18;
            int pxi = px - py * 18;
            int gy = y0 - 1 + py, gx = x0 - 1 + pxi;
            uint4 pk = make_uint4(0, 0, 0, 0);
            if (gy >= 0 && gy < H_ && gx >= 0 && gx < W_) {
                const float* sp = inb + (size_t)(chg * 8) * HW_ + (size_t)gy * W_ + gx;
                u32 wv[4];
                #pragma unroll
                for (int j = 0; j < 4; ++j) {
                    float a = sp[(size_t)(2 * j) * HW_];
                    float c = sp[(size_t)(2 * j + 1) * HW_];
                    wv[j] = f2bf(a) | ((u32)f2bf(c) << 16);
                }
                pk = make_uint4(wv[0], wv[1], wv[2], wv[3]);
            }
            *(uint4*)&Xt[px * 64 + ((chg * 8) ^ ((px & 7) << 3))] = pk;
        }
    }
    __syncthreads();

    const int lane = tid & 63, w = tid >> 6;
    const int g = lane >> 4, ln = lane & 15;
    const int wm = w & 1;
    const int wpar = w >> 1;

    u16* db = dst + (size_t)b * DIM_ * HW_;

    for (int c = 0; c < 8; ++c) {
        const int cb = c & 1;
        f32x4 acc[3];
        #pragma unroll
        for (int jj = 0; jj < 3; ++jj) acc[jj] = (f32x4){0.f, 0.f, 0.f, 0.f};
        short8 af[2];
        {
            int m = wm * 16 + ln;
            af[0] = *(const short8*)&Wtc[cb][m * 64 + ((g * 8) ^ ((m & 7) << 3))];
            af[1] = *(const short8*)&Wtc[cb][m * 64 + ((32 + g * 8) ^ ((m & 7) << 3))];
        }
        #pragma unroll
        for (int jj = 0; jj < 3; ++jj) {
            int j = jj * 4 + wpar;
            int px = j * 16 + ln;
            #pragma unroll
            for (int ks = 0; ks < 2; ++ks) {
                short8 bf = *(const short8*)&Xt[px * 64 + ((ks * 32 + g * 8) ^ ((px & 7) << 3))];
                acc[jj] = __builtin_amdgcn_mfma_f32_16x16x32_bf16(af[ks], bf, acc[jj], 0, 0, 0);
            }
        }

        if (c < 7) {
            const int row = tid >> 4, seg = tid & 15;
            float4 f = *(const float4*)(Wc + (size_t)((c + 1) * 32 + row) * 64 + seg * 4);
            uint2 pk;
            pk.x = f2bf(f.x) | ((u32)f2bf(f.y) << 16);
            pk.y = f2bf(f.z) | ((u32)f2bf(f.w) << 16);
            *(uint2*)&Wtc[cb ^ 1][row * 64 + ((seg * 4) ^ ((row & 7) << 3))] = pk;
        }

        #pragma unroll
        for (int jj = 0; jj < 3; ++jj) {
            int j = jj * 4 + wpar;
            int px = j * 16 + ln;
            #pragma unroll
            for (int r = 0; r < 4; ++r)
                Pt[(wm * 16 + g * 4 + r) * 196 + px] = f2bf(acc[jj][r]);
        }
        for (int i = tid; i < 288; i += 512) {
            int ch = i / 9, tap = i - ch * 9;
            wlds[tap * 36 + ch] = Wd[(size_t)(c * 32 + ch) * 9 + tap];
        }
        __syncthreads();

        {
            const int chl = tid >> 4;
            const int sub = tid & 15;
            const int oy = sub >> 1, ox0 = (sub & 1) * 8;
            float wr[9];
            #pragma unroll
            for (int t = 0; t < 9; ++t) wr[t] = wlds[t * 36 + chl];
            const u32* pw = (const u32*)&Pt[chl * 196];
            float R[3][10];
            #pragma unroll
            for (int dy = 0; dy < 3; ++dy) {
                int wbase = (oy + dy) * 9 + (ox0 >> 1);
                #pragma unroll
                for (int u = 0; u < 5; ++u) {
                    u32 wrd = pw[wbase + u];
                    R[dy][2 * u]     = bf2f((u16)wrd);
                    R[dy][2 * u + 1] = bf2f((u16)(wrd >> 16));
                }
            }
            float o[8];
            #pragma unroll
            for (int i = 0; i < 8; ++i) {
                float s = R[0][i] * wr[0];
                s = fmaf(R[0][i + 1], wr[1], s);
                s = fmaf(R[0][i + 2], wr[2], s);
                s = fmaf(R[1][i],     wr[3], s);
                s = fmaf(R[1][i + 1], wr[4], s);
                s = fmaf(R[1][i + 2], wr[5], s);
                s = fmaf(R[2][i],     wr[6], s);
                s = fmaf(R[2][i + 1], wr[7], s);
                s = fmaf(R[2][i + 2], wr[8], s);
                o[i] = s;
            }
            uint4 pk;
            pk.x = f2bf(o[0]) | ((u32)f2bf(o[1]) << 16);
            pk.y = f2bf(o[2]) | ((u32)f2bf(o[3]) << 16);
            pk.z = f2bf(o[4]) | ((u32)f2bf(o[5]) << 16);
            pk.w = f2bf(o[6]) | ((u32)f2bf(o[7]) << 16);
            *(uint4*)(db + (size_t)(c * 32 + chl) * HW_ + (size_t)(y0 + oy) * W_ + x0 + ox0) = pk;
        }
        if (c < 7) __syncthreads();
    }
}

// ---------------------------------------------------------------------------
// Gram via MFMA (verified): direct global fragments, sumsq = diagonals
// ---------------------------------------------------------------------------
__global__ __launch_bounds__(256) void gram_mfma_kernel(
    const u16* __restrict__ q, const u16* __restrict__ k,
    float* __restrict__ pgram, float* __restrict__ pssq, float* __restrict__ pssk)
{
    __shared__ float red[4][1024];
    __shared__ float redq[4][32];
    __shared__ float redk[4][32];

    const int bh = blockIdx.y;
    const int chunk = blockIdx.x;
    const int tid = threadIdx.x;
    const int lane = tid & 63, wid = tid >> 6;
    const int g = lane >> 4, ln = lane & 15;

    const size_t off = (size_t)(bh * 32 + ln) * HW_ + chunk * 2048 + wid * 512 + g * 8;
    const u16* qp = q + off;
    const u16* kp = k + off;

    f32x4 aqk[2][2] = {};
    f32x4 aqq[2] = {};
    f32x4 akk[2] = {};

    #pragma unroll 4
    for (int n = 0; n < 512; n += 32) {
        short8 qf[2], kf[2];
        qf[0] = *(const short8*)(qp + n);
        qf[1] = *(const short8*)(qp + (size_t)16 * HW_ + n);
        kf[0] = *(const short8*)(kp + n);
        kf[1] = *(const short8*)(kp + (size_t)16 * HW_ + n);
        #pragma unroll
        for (int ti = 0; ti < 2; ++ti)
            #pragma unroll
            for (int tj = 0; tj < 2; ++tj)
                aqk[ti][tj] = __builtin_amdgcn_mfma_f32_16x16x32_bf16(qf[ti], kf[tj], aqk[ti][tj], 0, 0, 0);
        #pragma unroll
        for (int ti = 0; ti < 2; ++ti) {
            aqq[ti] = __builtin_amdgcn_mfma_f32_16x16x32_bf16(qf[ti], qf[ti], aqq[ti], 0, 0, 0);
            akk[ti] = __builtin_amdgcn_mfma_f32_16x16x32_bf16(kf[ti], kf[ti], akk[ti], 0, 0, 0);
        }
    }

    #pragma unroll
    for (int ti = 0; ti < 2; ++ti)
        #pragma unroll
        for (int tj = 0; tj < 2; ++tj)
            #pragma unroll
            for (int r = 0; r < 4; ++r)
                red[wid][(ti * 16 + g * 4 + r) * 32 + tj * 16 + ln] = aqk[ti][tj][r];
    if ((ln >> 2) == g) {
        #pragma unroll
        for (int ti = 0; ti < 2; ++ti) {
            redq[wid][ti * 16 + ln] = aqq[ti][ln & 3];
            redk[wid][ti * 16 + ln] = akk[ti][ln & 3];
        }
    }
    __syncthreads();

    for (int p = tid; p < 1024; p += 256) {
        float s = red[0][p] + red[1][p] + red[2][p] + red[3][p];
        pgram[((size_t)bh * 8 + chunk) * 1024 + p] = s;
    }
    if (tid < 32) {
        pssq[((size_t)bh * 8 + chunk) * 32 + tid] =
            redq[0][tid] + redq[1][tid] + redq[2][tid] + redq[3][tid];
    } else if (tid < 64) {
        int j = tid & 31;
        pssk[((size_t)bh * 8 + chunk) * 32 + j] =
            redk[0][j] + redk[1][j] + redk[2][j] + redk[3][j];
    }
}

// ---------------------------------------------------------------------------
// reduce partials -> normalize -> softmax -> Amm(bf16) = Wproj_h @ attn
// ---------------------------------------------------------------------------
__global__ __launch_bounds__(256) void softproj_kernel(
    const float* __restrict__ pgram, const float* __restrict__ pssq,
    const float* __restrict__ pssk, const float* __restrict__ Wproj,
    const float* __restrict__ temp, u16* __restrict__ Amm)
{
    __shared__ float att[32][33];
    __shared__ float nq[32], nk[32];

    const int bh = blockIdx.x;
    const int h = bh & 7;
    const int b = bh >> 3;
    const int tid = threadIdx.x;

    for (int p = tid; p < 1024; p += 256) {
        float s = 0.f;
        #pragma unroll
        for (int c = 0; c < 8; ++c) s += pgram[((size_t)bh * 8 + c) * 1024 + p];
        att[p >> 5][p & 31] = s;
    }
    if (tid < 32) {
        float s = 0.f;
        #pragma unroll
        for (int c = 0; c < 8; ++c) s += pssq[((size_t)bh * 8 + c) * 32 + tid];
        nq[tid] = fmaxf(sqrtf(s), 1e-12f);
    } else if (tid < 64) {
        int i = tid & 31;
        float s = 0.f;
        #pragma unroll
        for (int c = 0; c < 8; ++c) s += pssk[((size_t)bh * 8 + c) * 32 + i];
        nk[i] = fmaxf(sqrtf(s), 1e-12f);
    }
    __syncthreads();

    const float T = temp[h];
    if (tid < 32) {
        int i = tid;
        float row[32];
        float mx = -1e30f;
        float qi = T / nq[i];
        #pragma unroll
        for (int j = 0; j < 32; ++j) {
            float v = att[i][j] * qi / nk[j];
            row[j] = v;
            mx = fmaxf(mx, v);
        }
        float s = 0.f;
        #pragma unroll
        for (int j = 0; j < 32; ++j) { float e = expf(row[j] - mx); row[j] = e; s += e; }
        float inv = 1.f / s;
        #pragma unroll
        for (int j = 0; j < 32; ++j) att[i][j] = row[j] * inv;
    }
    __syncthreads();

    const int o = tid;
    float wp[32];
    #pragma unroll
    for (int i2 = 0; i2 < 32; i2 += 4)
        *(float4*)&wp[i2] = *(const float4*)&Wproj[(size_t)o * DIM_ + h * 32 + i2];
    u16* arow = Amm + ((size_t)b * DIM_ + o) * DIM_ + h * 32;
    #pragma unroll
    for (int j = 0; j < 32; ++j) {
        float s = 0.f;
        #pragma unroll
        for (int i = 0; i < 32; ++i) s = fmaf(wp[i], att[i][j], s);
        arow[j] = f2bf(s);
    }
}

// ---------------------------------------------------------------------------
// cast Wfus [256][192] fp32 -> bf16 (once)
// ---------------------------------------------------------------------------
__global__ __launch_bounds__(256) void wfus_cast_kernel(
    const float* __restrict__ Wfus, u16* __restrict__ Afus)
{
    int idx = blockIdx.x * 256 + threadIdx.x;
    int base = idx * 8;
    float4 f0 = *(const float4*)(Wfus + base);
    float4 f1 = *(const float4*)(Wfus + base + 4);
    uint4 pk;
    pk.x = f2bf(f0.x) | ((u32)f2bf(f0.y) << 16);
    pk.y = f2bf(f0.z) | ((u32)f2bf(f0.w) << 16);
    pk.z = f2bf(f1.x) | ((u32)f2bf(f1.y) << 16);
    pk.w = f2bf(f1.z) | ((u32)f2bf(f1.w) << 16);
    *(uint4*)(Afus + base) = pk;
}

// ---------------------------------------------------------------------------
// final4 (R9-proven ~90us): 2 o-groups, 1-deep pipeline, age-ordered
// prefetch, __launch_bounds__(256,4). grid (128 px-panels, 2 o-groups, 8 b)
// ---------------------------------------------------------------------------
#define LOADB_F4(KC, W) do {                                                    \
    if ((KC) < 4) {                                                             \
        _Pragma("unroll") for (int i_ = 0; i_ < 2; ++i_) {                      \
            const u16* vb_ = vbuf + ((size_t)b * DIM_ + (KC) * 64 + (qq0 + 2 * i_) * 16) * HW_ + px0 + pxu; \
            _Pragma("unroll") for (int jj_ = 0; jj_ < 8; ++jj_)                 \
                W[i_][jj_] = (u32)vb_[(size_t)(2 * jj_) * HW_]                  \
                           | ((u32)vb_[(size_t)(2 * jj_ + 1) * HW_] << 16);     \
        }                                                                       \
    } else {                                                                    \
        const float* bp_ = ((KC) == 4) ? xin : ((KC) == 5) ? yin : zin;         \
        _Pragma("unroll") for (int i_ = 0; i_ < 2; ++i_) {                      \
            const float* sp_ = bp_ + ((size_t)b * CIN + (qq0 + 2 * i_) * 16) * HW_ + px0 + pxu; \
            _Pragma("unroll") for (int jj_ = 0; jj_ < 8; ++jj_)                 \
                W[i_][jj_] = (u32)f2bf(sp_[(size_t)(2 * jj_) * HW_])            \
                           | ((u32)f2bf(sp_[(size_t)(2 * jj_ + 1) * HW_]) << 16); \
        }                                                                       \
    } } while (0)

#define WRITEB_F4(BUF, W) do {                                                  \
    u16* dd_ = &Bl[BUF][pxu * 64];                                              \
    _Pragma("unroll") for (int i_ = 0; i_ < 2; ++i_) {                          \
        int qq_ = qq0 + 2 * i_;                                                 \
        *(uint4*)&dd_[(qq_ * 16)     ^ ((pxu & 7) << 3)] = make_uint4(W[i_][0], W[i_][1], W[i_][2], W[i_][3]); \
        *(uint4*)&dd_[(qq_ * 16 + 8) ^ ((pxu & 7) << 3)] = make_uint4(W[i_][4], W[i_][5], W[i_][6], W[i_][7]); \
    } } while (0)

#define LOADA_F4(KC, A) do {                                                    \
    _Pragma("unroll") for (int ks_ = 0; ks_ < 2; ++ks_)                         \
    _Pragma("unroll") for (int fm_ = 0; fm_ < 2; ++fm_) {                       \
        int m_ = m0 + fm_ * 16 + ln;                                            \
        const u16* ap_ = ((KC) < 4)                                             \
            ? Amm + ((size_t)b * DIM_ + m_) * DIM_ + (KC) * 64 + ks_ * 32 + g * 8 \
            : Afus + (size_t)m_ * 192 + ((KC) - 4) * 64 + ks_ * 32 + g * 8;     \
        A[ks_ * 2 + fm_] = *(const short8*)ap_;                                 \
    } } while (0)

__global__ __launch_bounds__(256, 4) void final4_kernel(
    const u16* __restrict__ Amm, const u16* __restrict__ Afus,
    const u16* __restrict__ vbuf,
    const float* __restrict__ xin, const float* __restrict__ yin,
    const float* __restrict__ zin, float* __restrict__ out)
{
    __shared__ u16 Bl[2][128 * 64];

    const int tid = threadIdx.x;
    const int px0 = blockIdx.x * 128;
    const int o0  = blockIdx.y * 128;
    const int b   = blockIdx.z;
    const int lane = tid & 63, wid = tid >> 6;
    const int g = lane >> 4, ln = lane & 15;
    const int m0 = o0 + wid * 32;
    const int pxu = tid & 127;
    const int qq0 = tid >> 7;      // 0 or 1

    f32x4 acc[2][8] = {};
    short8 aC[4], aN[4];
    u32 wN[2][8];

    LOADA_F4(0, aC);
    {
        u32 w0[2][8];
        LOADB_F4(0, w0);
        WRITEB_F4(0, w0);
    }
    __syncthreads();
    LOADA_F4(1, aN);
    LOADB_F4(1, wN);

    #pragma unroll
    for (int kc = 0; kc < 7; ++kc) {
        const int cur = kc & 1;

        #pragma unroll
        for (int ks = 0; ks < 2; ++ks)
            #pragma unroll
            for (int fn = 0; fn < 8; ++fn) {
                int p = fn * 16 + ln;
                short8 bf = *(const short8*)&Bl[cur][p * 64 + ((ks * 32 + g * 8) ^ ((p & 7) << 3))];
                acc[0][fn] = __builtin_amdgcn_mfma_f32_16x16x32_bf16(aC[ks * 2 + 0], bf, acc[0][fn], 0, 0, 0);
                acc[1][fn] = __builtin_amdgcn_mfma_f32_16x16x32_bf16(aC[ks * 2 + 1], bf, acc[1][fn], 0, 0, 0);
            }

        if (kc < 6) {
            WRITEB_F4(cur ^ 1, wN);
            __syncthreads();
            #pragma unroll
            for (int r = 0; r < 4; ++r) aC[r] = aN[r];
            if (kc < 5) {
                LOADA_F4(kc + 2, aN);
                LOADB_F4(kc + 2, wN);
            }
        }
    }

    float* op = out + (size_t)b * DIM_ * HW_;
    #pragma unroll
    for (int fm = 0; fm < 2; ++fm)
        #pragma unroll
        for (int fn = 0; fn < 8; ++fn)
            #pragma unroll
            for (int r = 0; r < 4; ++r) {
                int ch = m0 + fm * 16 + g * 4 + r;
                op[(size_t)ch * HW_ + px0 + fn * 16 + ln] = acc[fm][fn][r];
            }
}

// ---------------------------------------------------------------------------
extern "C" void kernel_launch(void* const* d_in, const int* in_sizes, int n_in,
                              void* d_out, int out_size, void* d_ws, size_t ws_size,
                              hipStream_t stream) {
    (void)in_sizes; (void)n_in; (void)out_size; (void)ws_size;

    const float* x     = (const float*)d_in[0];
    const float* y     = (const float*)d_in[1];
    const float* z     = (const float*)d_in[2];
    const float* Wq    = (const float*)d_in[3];
    const float* Wqd   = (const float*)d_in[4];
    const float* Wk    = (const float*)d_in[5];
    const float* Wkd   = (const float*)d_in[6];
    const float* Wv    = (const float*)d_in[7];
    const float* Wvd   = (const float*)d_in[8];
    const float* Wproj = (const float*)d_in[9];
    const float* Wfus  = (const float*)d_in[10];
    const float* temp  = (const float*)d_in[11];

    const size_t QELEMS = (size_t)B_ * DIM_ * HW_;   // 33.5M elems, 64 MiB bf16

    u16* qbuf = (u16*)d_out + QELEMS;         // q, dead after gram
    u16* kvbuf = (u16*)d_ws;                  // k, then v
    char* wsp = (char*)d_ws + QELEMS * sizeof(u16);
    float* pgram = (float*)wsp;                       wsp += 64 * 8 * 1024 * 4;
    float* pssq  = (float*)wsp;                       wsp += 64 * 8 * 32 * 4;
    float* pssk  = (float*)wsp;                       wsp += 64 * 8 * 32 * 4;
    u16*   Amm   = (u16*)wsp;                         wsp += (size_t)B_ * DIM_ * DIM_ * 2;
    u16*   Afus  = (u16*)wsp;

    dim3 fgrid(128, B_);

    wfus_cast_kernel<<<24, 256, 0, stream>>>(Wfus, Afus);
    convdw_kernel<<<fgrid, 512, 0, stream>>>(x, Wq, Wqd, qbuf);
    convdw_kernel<<<fgrid, 512, 0, stream>>>(y, Wk, Wkd, kvbuf);
    gram_mfma_kernel<<<dim3(8, 64), 256, 0, stream>>>(qbuf, kvbuf, pgram, pssq, pssk);
    softproj_kernel<<<64, 256, 0, stream>>>(pgram, pssq, pssk, Wproj, temp, Amm);
    convdw_kernel<<<fgrid, 512, 0, stream>>>(z, Wv, Wvd, kvbuf);
    final4_kernel<<<dim3(128, 2, B_), 256, 0, stream>>>(Amm, Afus, kvbuf, x, y, z, (float*)d_out);
}

// Round 18
// 264.861 us; speedup vs baseline: 2.0768x; 1.0099x over previous
//
#include <hip/hip_runtime.h>
#include <cstdint>

#define B_   8
#define CIN  64
#define DIM_ 256
#define H_   128
#define W_   128
#define HW_  (H_*W_)

typedef unsigned short u16;
typedef unsigned int   u32;
typedef short short8 __attribute__((ext_vector_type(8)));
typedef float f32x4  __attribute__((ext_vector_type(4)));

__device__ __forceinline__ u16 f2bf(float f) {
    u32 u = __float_as_uint(f);
    u32 r = (u + 0x7fffu + ((u >> 16) & 1u)) >> 16;
    return (u16)r;
}
__device__ __forceinline__ float bf2f(u16 h) {
    return __uint_as_float(((u32)h) << 16);
}

// ---------------------------------------------------------------------------
// convdw v4 (banked ~45us/tensor): FUSED conv1x1 + depthwise3x3.
// Tile 16x8 output (10x18 halo), LDS 45.8 KB, grid (128 tiles, 8 b), 512 thr.
// ---------------------------------------------------------------------------
__global__ __launch_bounds__(512, 6) void convdw_kernel(
    const float* __restrict__ in, const float* __restrict__ Wc,
    const float* __restrict__ Wd, u16* __restrict__ dst)
{
    __shared__ u16 Wtc[2][32 * 64];
    __shared__ u16 Xt[192 * 64];
    __shared__ u16 Pt[32 * 196];
    __shared__ float wlds[9 * 36];

    const int tid = threadIdx.x;
    const int tile = blockIdx.x;
    const int b = blockIdx.y;
    const int y0 = (tile >> 3) * 8;
    const int x0 = (tile & 7) * 16;

    {
        const int row = tid >> 4, seg = tid & 15;
        float4 f = *(const float4*)(Wc + (size_t)row * 64 + seg * 4);
        uint2 pk;
        pk.x = f2bf(f.x) | ((u32)f2bf(f.y) << 16);
        pk.y = f2bf(f.z) | ((u32)f2bf(f.w) << 16);
        *(uint2*)&Wtc[0][row * 64 + ((seg * 4) ^ ((row & 7) << 3))] = pk;
    }
    {
        const float* inb = in + (size_t)b * CIN * HW_;
        for (int i = tid; i < 1440; i += 512) {
            int chg = i / 180;
            int px = i - chg * 180;
            int py = px / 18;
            int pxi = px - py * 18;
            int gy = y0 - 1 + py, gx = x0 - 1 + pxi;
            uint4 pk = make_uint4(0, 0, 0, 0);
            if (gy >= 0 && gy < H_ && gx >= 0 && gx < W_) {
                const float* sp = inb + (size_t)(chg * 8) * HW_ + (size_t)gy * W_ + gx;
                u32 wv[4];
                #pragma unroll
                for (int j = 0; j < 4; ++j) {
                    float a = sp[(size_t)(2 * j) * HW_];
                    float c = sp[(size_t)(2 * j + 1) * HW_];
                    wv[j] = f2bf(a) | ((u32)f2bf(c) << 16);
                }
                pk = make_uint4(wv[0], wv[1], wv[2], wv[3]);
            }
            *(uint4*)&Xt[px * 64 + ((chg * 8) ^ ((px & 7) << 3))] = pk;
        }
    }
    __syncthreads();

    const int lane = tid & 63, w = tid >> 6;
    const int g = lane >> 4, ln = lane & 15;
    const int wm = w & 1;
    const int wpar = w >> 1;

    u16* db = dst + (size_t)b * DIM_ * HW_;

    for (int c = 0; c < 8; ++c) {
        const int cb = c & 1;
        f32x4 acc[3];
        #pragma unroll
        for (int jj = 0; jj < 3; ++jj) acc[jj] = (f32x4){0.f, 0.f, 0.f, 0.f};
        short8 af[2];
        {
            int m = wm * 16 + ln;
            af[0] = *(const short8*)&Wtc[cb][m * 64 + ((g * 8) ^ ((m & 7) << 3))];
            af[1] = *(const short8*)&Wtc[cb][m * 64 + ((32 + g * 8) ^ ((m & 7) << 3))];
        }
        #pragma unroll
        for (int jj = 0; jj < 3; ++jj) {
            int j = jj * 4 + wpar;
            int px = j * 16 + ln;
            #pragma unroll
            for (int ks = 0; ks < 2; ++ks) {
                short8 bf = *(const short8*)&Xt[px * 64 + ((ks * 32 + g * 8) ^ ((px & 7) << 3))];
                acc[jj] = __builtin_amdgcn_mfma_f32_16x16x32_bf16(af[ks], bf, acc[jj], 0, 0, 0);
            }
        }

        if (c < 7) {
            const int row = tid >> 4, seg = tid & 15;
            float4 f = *(const float4*)(Wc + (size_t)((c + 1) * 32 + row) * 64 + seg * 4);
            uint2 pk;
            pk.x = f2bf(f.x) | ((u32)f2bf(f.y) << 16);
            pk.y = f2bf(f.z) | ((u32)f2bf(f.w) << 16);
            *(uint2*)&Wtc[cb ^ 1][row * 64 + ((seg * 4) ^ ((row & 7) << 3))] = pk;
        }

        #pragma unroll
        for (int jj = 0; jj < 3; ++jj) {
            int j = jj * 4 + wpar;
            int px = j * 16 + ln;
            #pragma unroll
            for (int r = 0; r < 4; ++r)
                Pt[(wm * 16 + g * 4 + r) * 196 + px] = f2bf(acc[jj][r]);
        }
        for (int i = tid; i < 288; i += 512) {
            int ch = i / 9, tap = i - ch * 9;
            wlds[tap * 36 + ch] = Wd[(size_t)(c * 32 + ch) * 9 + tap];
        }
        __syncthreads();

        {
            const int chl = tid >> 4;
            const int sub = tid & 15;
            const int oy = sub >> 1, ox0 = (sub & 1) * 8;
            float wr[9];
            #pragma unroll
            for (int t = 0; t < 9; ++t) wr[t] = wlds[t * 36 + chl];
            const u32* pw = (const u32*)&Pt[chl * 196];
            float R[3][10];
            #pragma unroll
            for (int dy = 0; dy < 3; ++dy) {
                int wbase = (oy + dy) * 9 + (ox0 >> 1);
                #pragma unroll
                for (int u = 0; u < 5; ++u) {
                    u32 wrd = pw[wbase + u];
                    R[dy][2 * u]     = bf2f((u16)wrd);
                    R[dy][2 * u + 1] = bf2f((u16)(wrd >> 16));
                }
            }
            float o[8];
            #pragma unroll
            for (int i = 0; i < 8; ++i) {
                float s = R[0][i] * wr[0];
                s = fmaf(R[0][i + 1], wr[1], s);
                s = fmaf(R[0][i + 2], wr[2], s);
                s = fmaf(R[1][i],     wr[3], s);
                s = fmaf(R[1][i + 1], wr[4], s);
                s = fmaf(R[1][i + 2], wr[5], s);
                s = fmaf(R[2][i],     wr[6], s);
                s = fmaf(R[2][i + 1], wr[7], s);
                s = fmaf(R[2][i + 2], wr[8], s);
                o[i] = s;
            }
            uint4 pk;
            pk.x = f2bf(o[0]) | ((u32)f2bf(o[1]) << 16);
            pk.y = f2bf(o[2]) | ((u32)f2bf(o[3]) << 16);
            pk.z = f2bf(o[4]) | ((u32)f2bf(o[5]) << 16);
            pk.w = f2bf(o[6]) | ((u32)f2bf(o[7]) << 16);
            *(uint4*)(db + (size_t)(c * 32 + chl) * HW_ + (size_t)(y0 + oy) * W_ + x0 + ox0) = pk;
        }
        if (c < 7) __syncthreads();
    }
}

// ---------------------------------------------------------------------------
// Gram via MFMA, v2: 16 n-chunks (was 8) -> 1024 blocks = 4/CU, 2x TLP
// for the BW-bound stream. Per wave: 256-elem slice, 8 K-iterations.
// grid (16 chunks, 64 bh), block 256.
// ---------------------------------------------------------------------------
__global__ __launch_bounds__(256) void gram_mfma_kernel(
    const u16* __restrict__ q, const u16* __restrict__ k,
    float* __restrict__ pgram, float* __restrict__ pssq, float* __restrict__ pssk)
{
    __shared__ float red[4][1024];
    __shared__ float redq[4][32];
    __shared__ float redk[4][32];

    const int bh = blockIdx.y;
    const int chunk = blockIdx.x;
    const int tid = threadIdx.x;
    const int lane = tid & 63, wid = tid >> 6;
    const int g = lane >> 4, ln = lane & 15;

    const size_t off = (size_t)(bh * 32 + ln) * HW_ + chunk * 1024 + wid * 256 + g * 8;
    const u16* qp = q + off;
    const u16* kp = k + off;

    f32x4 aqk[2][2] = {};
    f32x4 aqq[2] = {};
    f32x4 akk[2] = {};

    #pragma unroll 4
    for (int n = 0; n < 256; n += 32) {
        short8 qf[2], kf[2];
        qf[0] = *(const short8*)(qp + n);
        qf[1] = *(const short8*)(qp + (size_t)16 * HW_ + n);
        kf[0] = *(const short8*)(kp + n);
        kf[1] = *(const short8*)(kp + (size_t)16 * HW_ + n);
        #pragma unroll
        for (int ti = 0; ti < 2; ++ti)
            #pragma unroll
            for (int tj = 0; tj < 2; ++tj)
                aqk[ti][tj] = __builtin_amdgcn_mfma_f32_16x16x32_bf16(qf[ti], kf[tj], aqk[ti][tj], 0, 0, 0);
        #pragma unroll
        for (int ti = 0; ti < 2; ++ti) {
            aqq[ti] = __builtin_amdgcn_mfma_f32_16x16x32_bf16(qf[ti], qf[ti], aqq[ti], 0, 0, 0);
            akk[ti] = __builtin_amdgcn_mfma_f32_16x16x32_bf16(kf[ti], kf[ti], akk[ti], 0, 0, 0);
        }
    }

    #pragma unroll
    for (int ti = 0; ti < 2; ++ti)
        #pragma unroll
        for (int tj = 0; tj < 2; ++tj)
            #pragma unroll
            for (int r = 0; r < 4; ++r)
                red[wid][(ti * 16 + g * 4 + r) * 32 + tj * 16 + ln] = aqk[ti][tj][r];
    if ((ln >> 2) == g) {
        #pragma unroll
        for (int ti = 0; ti < 2; ++ti) {
            redq[wid][ti * 16 + ln] = aqq[ti][ln & 3];
            redk[wid][ti * 16 + ln] = akk[ti][ln & 3];
        }
    }
    __syncthreads();

    for (int p = tid; p < 1024; p += 256) {
        float s = red[0][p] + red[1][p] + red[2][p] + red[3][p];
        pgram[((size_t)bh * 16 + chunk) * 1024 + p] = s;
    }
    if (tid < 32) {
        pssq[((size_t)bh * 16 + chunk) * 32 + tid] =
            redq[0][tid] + redq[1][tid] + redq[2][tid] + redq[3][tid];
    } else if (tid < 64) {
        int j = tid & 31;
        pssk[((size_t)bh * 16 + chunk) * 32 + j] =
            redk[0][j] + redk[1][j] + redk[2][j] + redk[3][j];
    }
}

// ---------------------------------------------------------------------------
// reduce 16 partials -> normalize -> softmax -> Amm(bf16) = Wproj_h @ attn
// ---------------------------------------------------------------------------
__global__ __launch_bounds__(256) void softproj_kernel(
    const float* __restrict__ pgram, const float* __restrict__ pssq,
    const float* __restrict__ pssk, const float* __restrict__ Wproj,
    const float* __restrict__ temp, u16* __restrict__ Amm)
{
    __shared__ float att[32][33];
    __shared__ float nq[32], nk[32];

    const int bh = blockIdx.x;
    const int h = bh & 7;
    const int b = bh >> 3;
    const int tid = threadIdx.x;

    for (int p = tid; p < 1024; p += 256) {
        float s = 0.f;
        #pragma unroll
        for (int c = 0; c < 16; ++c) s += pgram[((size_t)bh * 16 + c) * 1024 + p];
        att[p >> 5][p & 31] = s;
    }
    if (tid < 32) {
        float s = 0.f;
        #pragma unroll
        for (int c = 0; c < 16; ++c) s += pssq[((size_t)bh * 16 + c) * 32 + tid];
        nq[tid] = fmaxf(sqrtf(s), 1e-12f);
    } else if (tid < 64) {
        int i = tid & 31;
        float s = 0.f;
        #pragma unroll
        for (int c = 0; c < 16; ++c) s += pssk[((size_t)bh * 16 + c) * 32 + i];
        nk[i] = fmaxf(sqrtf(s), 1e-12f);
    }
    __syncthreads();

    const float T = temp[h];
    if (tid < 32) {
        int i = tid;
        float row[32];
        float mx = -1e30f;
        float qi = T / nq[i];
        #pragma unroll
        for (int j = 0; j < 32; ++j) {
            float v = att[i][j] * qi / nk[j];
            row[j] = v;
            mx = fmaxf(mx, v);
        }
        float s = 0.f;
        #pragma unroll
        for (int j = 0; j < 32; ++j) { float e = expf(row[j] - mx); row[j] = e; s += e; }
        float inv = 1.f / s;
        #pragma unroll
        for (int j = 0; j < 32; ++j) att[i][j] = row[j] * inv;
    }
    __syncthreads();

    const int o = tid;
    float wp[32];
    #pragma unroll
    for (int i2 = 0; i2 < 32; i2 += 4)
        *(float4*)&wp[i2] = *(const float4*)&Wproj[(size_t)o * DIM_ + h * 32 + i2];
    u16* arow = Amm + ((size_t)b * DIM_ + o) * DIM_ + h * 32;
    #pragma unroll
    for (int j = 0; j < 32; ++j) {
        float s = 0.f;
        #pragma unroll
        for (int i = 0; i < 32; ++i) s = fmaf(wp[i], att[i][j], s);
        arow[j] = f2bf(s);
    }
}

// ---------------------------------------------------------------------------
// cast Wfus [256][192] fp32 -> bf16 (once)
// ---------------------------------------------------------------------------
__global__ __launch_bounds__(256) void wfus_cast_kernel(
    const float* __restrict__ Wfus, u16* __restrict__ Afus)
{
    int idx = blockIdx.x * 256 + threadIdx.x;
    int base = idx * 8;
    float4 f0 = *(const float4*)(Wfus + base);
    float4 f1 = *(const float4*)(Wfus + base + 4);
    uint4 pk;
    pk.x = f2bf(f0.x) | ((u32)f2bf(f0.y) << 16);
    pk.y = f2bf(f0.z) | ((u32)f2bf(f0.w) << 16);
    pk.z = f2bf(f1.x) | ((u32)f2bf(f1.y) << 16);
    pk.w = f2bf(f1.z) | ((u32)f2bf(f1.w) << 16);
    *(uint4*)(Afus + base) = pk;
}

// ---------------------------------------------------------------------------
// final4 (R9-proven ~90us, FROZEN): 2 o-groups, 1-deep pipeline, age-ordered
// prefetch, __launch_bounds__(256,4). grid (128 px-panels, 2 o-groups, 8 b)
// ---------------------------------------------------------------------------
#define LOADB_F4(KC, W) do {                                                    \
    if ((KC) < 4) {                                                             \
        _Pragma("unroll") for (int i_ = 0; i_ < 2; ++i_) {                      \
            const u16* vb_ = vbuf + ((size_t)b * DIM_ + (KC) * 64 + (qq0 + 2 * i_) * 16) * HW_ + px0 + pxu; \
            _Pragma("unroll") for (int jj_ = 0; jj_ < 8; ++jj_)                 \
                W[i_][jj_] = (u32)vb_[(size_t)(2 * jj_) * HW_]                  \
                           | ((u32)vb_[(size_t)(2 * jj_ + 1) * HW_] << 16);     \
        }                                                                       \
    } else {                                                                    \
        const float* bp_ = ((KC) == 4) ? xin : ((KC) == 5) ? yin : zin;         \
        _Pragma("unroll") for (int i_ = 0; i_ < 2; ++i_) {                      \
            const float* sp_ = bp_ + ((size_t)b * CIN + (qq0 + 2 * i_) * 16) * HW_ + px0 + pxu; \
            _Pragma("unroll") for (int jj_ = 0; jj_ < 8; ++jj_)                 \
                W[i_][jj_] = (u32)f2bf(sp_[(size_t)(2 * jj_) * HW_])            \
                           | ((u32)f2bf(sp_[(size_t)(2 * jj_ + 1) * HW_]) << 16); \
        }                                                                       \
    } } while (0)

#define WRITEB_F4(BUF, W) do {                                                  \
    u16* dd_ = &Bl[BUF][pxu * 64];                                              \
    _Pragma("unroll") for (int i_ = 0; i_ < 2; ++i_) {                          \
        int qq_ = qq0 + 2 * i_;                                                 \
        *(uint4*)&dd_[(qq_ * 16)     ^ ((pxu & 7) << 3)] = make_uint4(W[i_][0], W[i_][1], W[i_][2], W[i_][3]); \
        *(uint4*)&dd_[(qq_ * 16 + 8) ^ ((pxu & 7) << 3)] = make_uint4(W[i_][4], W[i_][5], W[i_][6], W[i_][7]); \
    } } while (0)

#define LOADA_F4(KC, A) do {                                                    \
    _Pragma("unroll") for (int ks_ = 0; ks_ < 2; ++ks_)                         \
    _Pragma("unroll") for (int fm_ = 0; fm_ < 2; ++fm_) {                       \
        int m_ = m0 + fm_ * 16 + ln;                                            \
        const u16* ap_ = ((KC) < 4)                                             \
            ? Amm + ((size_t)b * DIM_ + m_) * DIM_ + (KC) * 64 + ks_ * 32 + g * 8 \
            : Afus + (size_t)m_ * 192 + ((KC) - 4) * 64 + ks_ * 32 + g * 8;     \
        A[ks_ * 2 + fm_] = *(const short8*)ap_;                                 \
    } } while (0)

__global__ __launch_bounds__(256, 4) void final4_kernel(
    const u16* __restrict__ Amm, const u16* __restrict__ Afus,
    const u16* __restrict__ vbuf,
    const float* __restrict__ xin, const float* __restrict__ yin,
    const float* __restrict__ zin, float* __restrict__ out)
{
    __shared__ u16 Bl[2][128 * 64];

    const int tid = threadIdx.x;
    const int px0 = blockIdx.x * 128;
    const int o0  = blockIdx.y * 128;
    const int b   = blockIdx.z;
    const int lane = tid & 63, wid = tid >> 6;
    const int g = lane >> 4, ln = lane & 15;
    const int m0 = o0 + wid * 32;
    const int pxu = tid & 127;
    const int qq0 = tid >> 7;      // 0 or 1

    f32x4 acc[2][8] = {};
    short8 aC[4], aN[4];
    u32 wN[2][8];

    LOADA_F4(0, aC);
    {
        u32 w0[2][8];
        LOADB_F4(0, w0);
        WRITEB_F4(0, w0);
    }
    __syncthreads();
    LOADA_F4(1, aN);
    LOADB_F4(1, wN);

    #pragma unroll
    for (int kc = 0; kc < 7; ++kc) {
        const int cur = kc & 1;

        #pragma unroll
        for (int ks = 0; ks < 2; ++ks)
            #pragma unroll
            for (int fn = 0; fn < 8; ++fn) {
                int p = fn * 16 + ln;
                short8 bf = *(const short8*)&Bl[cur][p * 64 + ((ks * 32 + g * 8) ^ ((p & 7) << 3))];
                acc[0][fn] = __builtin_amdgcn_mfma_f32_16x16x32_bf16(aC[ks * 2 + 0], bf, acc[0][fn], 0, 0, 0);
                acc[1][fn] = __builtin_amdgcn_mfma_f32_16x16x32_bf16(aC[ks * 2 + 1], bf, acc[1][fn], 0, 0, 0);
            }

        if (kc < 6) {
            WRITEB_F4(cur ^ 1, wN);
            __syncthreads();
            #pragma unroll
            for (int r = 0; r < 4; ++r) aC[r] = aN[r];
            if (kc < 5) {
                LOADA_F4(kc + 2, aN);
                LOADB_F4(kc + 2, wN);
            }
        }
    }

    float* op = out + (size_t)b * DIM_ * HW_;
    #pragma unroll
    for (int fm = 0; fm < 2; ++fm)
        #pragma unroll
        for (int fn = 0; fn < 8; ++fn)
            #pragma unroll
            for (int r = 0; r < 4; ++r) {
                int ch = m0 + fm * 16 + g * 4 + r;
                op[(size_t)ch * HW_ + px0 + fn * 16 + ln] = acc[fm][fn][r];
            }
}

// ---------------------------------------------------------------------------
extern "C" void kernel_launch(void* const* d_in, const int* in_sizes, int n_in,
                              void* d_out, int out_size, void* d_ws, size_t ws_size,
                              hipStream_t stream) {
    (void)in_sizes; (void)n_in; (void)out_size; (void)ws_size;

    const float* x     = (const float*)d_in[0];
    const float* y     = (const float*)d_in[1];
    const float* z     = (const float*)d_in[2];
    const float* Wq    = (const float*)d_in[3];
    const float* Wqd   = (const float*)d_in[4];
    const float* Wk    = (const float*)d_in[5];
    const float* Wkd   = (const float*)d_in[6];
    const float* Wv    = (const float*)d_in[7];
    const float* Wvd   = (const float*)d_in[8];
    const float* Wproj = (const float*)d_in[9];
    const float* Wfus  = (const float*)d_in[10];
    const float* temp  = (const float*)d_in[11];

    const size_t QELEMS = (size_t)B_ * DIM_ * HW_;   // 33.5M elems, 64 MiB bf16

    u16* qbuf = (u16*)d_out + QELEMS;         // q, dead after gram
    u16* kvbuf = (u16*)d_ws;                  // k, then v
    char* wsp = (char*)d_ws + QELEMS * sizeof(u16);
    float* pgram = (float*)wsp;                       wsp += 64 * 16 * 1024 * 4;
    float* pssq  = (float*)wsp;                       wsp += 64 * 16 * 32 * 4;
    float* pssk  = (float*)wsp;                       wsp += 64 * 16 * 32 * 4;
    u16*   Amm   = (u16*)wsp;                         wsp += (size_t)B_ * DIM_ * DIM_ * 2;
    u16*   Afus  = (u16*)wsp;

    dim3 fgrid(128, B_);

    wfus_cast_kernel<<<24, 256, 0, stream>>>(Wfus, Afus);
    convdw_kernel<<<fgrid, 512, 0, stream>>>(x, Wq, Wqd, qbuf);
    convdw_kernel<<<fgrid, 512, 0, stream>>>(y, Wk, Wkd, kvbuf);
    gram_mfma_kernel<<<dim3(16, 64), 256, 0, stream>>>(qbuf, kvbuf, pgram, pssq, pssk);
    softproj_kernel<<<64, 256, 0, stream>>>(pgram, pssq, pssk, Wproj, temp, Amm);
    convdw_kernel<<<fgrid, 512, 0, stream>>>(z, Wv, Wvd, kvbuf);
    final4_kernel<<<dim3(128, 2, B_), 256, 0, stream>>>(Amm, Afus, kvbuf, x, y, z, (float*)d_out);
}

// Round 19
// 256.670 us; speedup vs baseline: 2.1431x; 1.0319x over previous
//
#include <hip/hip_runtime.h>
#include <cstdint>

#define B_   8
#define CIN  64
#define DIM_ 256
#define H_   128
#define W_   128
#define HW_  (H_*W_)

typedef unsigned short u16;
typedef unsigned int   u32;
typedef short short8 __attribute__((ext_vector_type(8)));
typedef float f32x4  __attribute__((ext_vector_type(4)));

__device__ __forceinline__ u16 f2bf(float f) {
    u32 u = __float_as_uint(f);
    u32 r = (u + 0x7fffu + ((u >> 16) & 1u)) >> 16;
    return (u16)r;
}
__device__ __forceinline__ float bf2f(u16 h) {
    return __uint_as_float(((u32)h) << 16);
}

// ---------------------------------------------------------------------------
// convdw v4 (banked ~45us/tensor): FUSED conv1x1 + depthwise3x3.
// Tile 16x8 output (10x18 halo), LDS 45.8 KB, 512 thr.
// DUAL-TENSOR: blockIdx.z selects param set -> x and y processed in ONE
// launch (removes an inter-kernel drain boundary). z-tensor launch uses
// gridDim.z=1 with set 0.
// ---------------------------------------------------------------------------
__global__ __launch_bounds__(512, 6) void convdw_kernel(
    const float* __restrict__ in0, const float* __restrict__ Wc0,
    const float* __restrict__ Wd0, u16* __restrict__ dst0,
    const float* __restrict__ in1, const float* __restrict__ Wc1,
    const float* __restrict__ Wd1, u16* __restrict__ dst1)
{
    __shared__ u16 Wtc[2][32 * 64];
    __shared__ u16 Xt[192 * 64];
    __shared__ u16 Pt[32 * 196];
    __shared__ float wlds[9 * 36];

    const int tid = threadIdx.x;
    const int tile = blockIdx.x;
    const int b = blockIdx.y;
    const int ts = blockIdx.z;
    const float* in = ts ? in1 : in0;
    const float* Wc = ts ? Wc1 : Wc0;
    const float* Wd = ts ? Wd1 : Wd0;
    u16* dst        = ts ? dst1 : dst0;
    const int y0 = (tile >> 3) * 8;
    const int x0 = (tile & 7) * 16;

    {
        const int row = tid >> 4, seg = tid & 15;
        float4 f = *(const float4*)(Wc + (size_t)row * 64 + seg * 4);
        uint2 pk;
        pk.x = f2bf(f.x) | ((u32)f2bf(f.y) << 16);
        pk.y = f2bf(f.z) | ((u32)f2bf(f.w) << 16);
        *(uint2*)&Wtc[0][row * 64 + ((seg * 4) ^ ((row & 7) << 3))] = pk;
    }
    {
        const float* inb = in + (size_t)b * CIN * HW_;
        for (int i = tid; i < 1440; i += 512) {
            int chg = i / 180;
            int px = i - chg * 180;
            int py = px / 18;
            int pxi = px - py * 18;
            int gy = y0 - 1 + py, gx = x0 - 1 + pxi;
            uint4 pk = make_uint4(0, 0, 0, 0);
            if (gy >= 0 && gy < H_ && gx >= 0 && gx < W_) {
                const float* sp = inb + (size_t)(chg * 8) * HW_ + (size_t)gy * W_ + gx;
                u32 wv[4];
                #pragma unroll
                for (int j = 0; j < 4; ++j) {
                    float a = sp[(size_t)(2 * j) * HW_];
                    float c = sp[(size_t)(2 * j + 1) * HW_];
                    wv[j] = f2bf(a) | ((u32)f2bf(c) << 16);
                }
                pk = make_uint4(wv[0], wv[1], wv[2], wv[3]);
            }
            *(uint4*)&Xt[px * 64 + ((chg * 8) ^ ((px & 7) << 3))] = pk;
        }
    }
    __syncthreads();

    const int lane = tid & 63, w = tid >> 6;
    const int g = lane >> 4, ln = lane & 15;
    const int wm = w & 1;
    const int wpar = w >> 1;

    u16* db = dst + (size_t)b * DIM_ * HW_;

    for (int c = 0; c < 8; ++c) {
        const int cb = c & 1;
        f32x4 acc[3];
        #pragma unroll
        for (int jj = 0; jj < 3; ++jj) acc[jj] = (f32x4){0.f, 0.f, 0.f, 0.f};
        short8 af[2];
        {
            int m = wm * 16 + ln;
            af[0] = *(const short8*)&Wtc[cb][m * 64 + ((g * 8) ^ ((m & 7) << 3))];
            af[1] = *(const short8*)&Wtc[cb][m * 64 + ((32 + g * 8) ^ ((m & 7) << 3))];
        }
        #pragma unroll
        for (int jj = 0; jj < 3; ++jj) {
            int j = jj * 4 + wpar;
            int px = j * 16 + ln;
            #pragma unroll
            for (int ks = 0; ks < 2; ++ks) {
                short8 bf = *(const short8*)&Xt[px * 64 + ((ks * 32 + g * 8) ^ ((px & 7) << 3))];
                acc[jj] = __builtin_amdgcn_mfma_f32_16x16x32_bf16(af[ks], bf, acc[jj], 0, 0, 0);
            }
        }

        if (c < 7) {
            const int row = tid >> 4, seg = tid & 15;
            float4 f = *(const float4*)(Wc + (size_t)((c + 1) * 32 + row) * 64 + seg * 4);
            uint2 pk;
            pk.x = f2bf(f.x) | ((u32)f2bf(f.y) << 16);
            pk.y = f2bf(f.z) | ((u32)f2bf(f.w) << 16);
            *(uint2*)&Wtc[cb ^ 1][row * 64 + ((seg * 4) ^ ((row & 7) << 3))] = pk;
        }

        #pragma unroll
        for (int jj = 0; jj < 3; ++jj) {
            int j = jj * 4 + wpar;
            int px = j * 16 + ln;
            #pragma unroll
            for (int r = 0; r < 4; ++r)
                Pt[(wm * 16 + g * 4 + r) * 196 + px] = f2bf(acc[jj][r]);
        }
        for (int i = tid; i < 288; i += 512) {
            int ch = i / 9, tap = i - ch * 9;
            wlds[tap * 36 + ch] = Wd[(size_t)(c * 32 + ch) * 9 + tap];
        }
        __syncthreads();

        {
            const int chl = tid >> 4;
            const int sub = tid & 15;
            const int oy = sub >> 1, ox0 = (sub & 1) * 8;
            float wr[9];
            #pragma unroll
            for (int t = 0; t < 9; ++t) wr[t] = wlds[t * 36 + chl];
            const u32* pw = (const u32*)&Pt[chl * 196];
            float R[3][10];
            #pragma unroll
            for (int dy = 0; dy < 3; ++dy) {
                int wbase = (oy + dy) * 9 + (ox0 >> 1);
                #pragma unroll
                for (int u = 0; u < 5; ++u) {
                    u32 wrd = pw[wbase + u];
                    R[dy][2 * u]     = bf2f((u16)wrd);
                    R[dy][2 * u + 1] = bf2f((u16)(wrd >> 16));
                }
            }
            float o[8];
            #pragma unroll
            for (int i = 0; i < 8; ++i) {
                float s = R[0][i] * wr[0];
                s = fmaf(R[0][i + 1], wr[1], s);
                s = fmaf(R[0][i + 2], wr[2], s);
                s = fmaf(R[1][i],     wr[3], s);
                s = fmaf(R[1][i + 1], wr[4], s);
                s = fmaf(R[1][i + 2], wr[5], s);
                s = fmaf(R[2][i],     wr[6], s);
                s = fmaf(R[2][i + 1], wr[7], s);
                s = fmaf(R[2][i + 2], wr[8], s);
                o[i] = s;
            }
            uint4 pk;
            pk.x = f2bf(o[0]) | ((u32)f2bf(o[1]) << 16);
            pk.y = f2bf(o[2]) | ((u32)f2bf(o[3]) << 16);
            pk.z = f2bf(o[4]) | ((u32)f2bf(o[5]) << 16);
            pk.w = f2bf(o[6]) | ((u32)f2bf(o[7]) << 16);
            *(uint4*)(db + (size_t)(c * 32 + chl) * HW_ + (size_t)(y0 + oy) * W_ + x0 + ox0) = pk;
        }
        if (c < 7) __syncthreads();
    }
}

// ---------------------------------------------------------------------------
// Gram via MFMA, 16 n-chunks: 1024 blocks, direct global fragments,
// sumsq = diagonals. grid (16, 64), block 256.
// ---------------------------------------------------------------------------
__global__ __launch_bounds__(256) void gram_mfma_kernel(
    const u16* __restrict__ q, const u16* __restrict__ k,
    float* __restrict__ pgram, float* __restrict__ pssq, float* __restrict__ pssk)
{
    __shared__ float red[4][1024];
    __shared__ float redq[4][32];
    __shared__ float redk[4][32];

    const int bh = blockIdx.y;
    const int chunk = blockIdx.x;
    const int tid = threadIdx.x;
    const int lane = tid & 63, wid = tid >> 6;
    const int g = lane >> 4, ln = lane & 15;

    const size_t off = (size_t)(bh * 32 + ln) * HW_ + chunk * 1024 + wid * 256 + g * 8;
    const u16* qp = q + off;
    const u16* kp = k + off;

    f32x4 aqk[2][2] = {};
    f32x4 aqq[2] = {};
    f32x4 akk[2] = {};

    #pragma unroll 4
    for (int n = 0; n < 256; n += 32) {
        short8 qf[2], kf[2];
        qf[0] = *(const short8*)(qp + n);
        qf[1] = *(const short8*)(qp + (size_t)16 * HW_ + n);
        kf[0] = *(const short8*)(kp + n);
        kf[1] = *(const short8*)(kp + (size_t)16 * HW_ + n);
        #pragma unroll
        for (int ti = 0; ti < 2; ++ti)
            #pragma unroll
            for (int tj = 0; tj < 2; ++tj)
                aqk[ti][tj] = __builtin_amdgcn_mfma_f32_16x16x32_bf16(qf[ti], kf[tj], aqk[ti][tj], 0, 0, 0);
        #pragma unroll
        for (int ti = 0; ti < 2; ++ti) {
            aqq[ti] = __builtin_amdgcn_mfma_f32_16x16x32_bf16(qf[ti], qf[ti], aqq[ti], 0, 0, 0);
            akk[ti] = __builtin_amdgcn_mfma_f32_16x16x32_bf16(kf[ti], kf[ti], akk[ti], 0, 0, 0);
        }
    }

    #pragma unroll
    for (int ti = 0; ti < 2; ++ti)
        #pragma unroll
        for (int tj = 0; tj < 2; ++tj)
            #pragma unroll
            for (int r = 0; r < 4; ++r)
                red[wid][(ti * 16 + g * 4 + r) * 32 + tj * 16 + ln] = aqk[ti][tj][r];
    if ((ln >> 2) == g) {
        #pragma unroll
        for (int ti = 0; ti < 2; ++ti) {
            redq[wid][ti * 16 + ln] = aqq[ti][ln & 3];
            redk[wid][ti * 16 + ln] = akk[ti][ln & 3];
        }
    }
    __syncthreads();

    for (int p = tid; p < 1024; p += 256) {
        float s = red[0][p] + red[1][p] + red[2][p] + red[3][p];
        pgram[((size_t)bh * 16 + chunk) * 1024 + p] = s;
    }
    if (tid < 32) {
        pssq[((size_t)bh * 16 + chunk) * 32 + tid] =
            redq[0][tid] + redq[1][tid] + redq[2][tid] + redq[3][tid];
    } else if (tid < 64) {
        int j = tid & 31;
        pssk[((size_t)bh * 16 + chunk) * 32 + j] =
            redk[0][j] + redk[1][j] + redk[2][j] + redk[3][j];
    }
}

// ---------------------------------------------------------------------------
// reduce 16 partials -> normalize -> softmax -> Amm(bf16) = Wproj_h @ attn
// ---------------------------------------------------------------------------
__global__ __launch_bounds__(256) void softproj_kernel(
    const float* __restrict__ pgram, const float* __restrict__ pssq,
    const float* __restrict__ pssk, const float* __restrict__ Wproj,
    const float* __restrict__ temp, u16* __restrict__ Amm)
{
    __shared__ float att[32][33];
    __shared__ float nq[32], nk[32];

    const int bh = blockIdx.x;
    const int h = bh & 7;
    const int b = bh >> 3;
    const int tid = threadIdx.x;

    for (int p = tid; p < 1024; p += 256) {
        float s = 0.f;
        #pragma unroll
        for (int c = 0; c < 16; ++c) s += pgram[((size_t)bh * 16 + c) * 1024 + p];
        att[p >> 5][p & 31] = s;
    }
    if (tid < 32) {
        float s = 0.f;
        #pragma unroll
        for (int c = 0; c < 16; ++c) s += pssq[((size_t)bh * 16 + c) * 32 + tid];
        nq[tid] = fmaxf(sqrtf(s), 1e-12f);
    } else if (tid < 64) {
        int i = tid & 31;
        float s = 0.f;
        #pragma unroll
        for (int c = 0; c < 16; ++c) s += pssk[((size_t)bh * 16 + c) * 32 + i];
        nk[i] = fmaxf(sqrtf(s), 1e-12f);
    }
    __syncthreads();

    const float T = temp[h];
    if (tid < 32) {
        int i = tid;
        float row[32];
        float mx = -1e30f;
        float qi = T / nq[i];
        #pragma unroll
        for (int j = 0; j < 32; ++j) {
            float v = att[i][j] * qi / nk[j];
            row[j] = v;
            mx = fmaxf(mx, v);
        }
        float s = 0.f;
        #pragma unroll
        for (int j = 0; j < 32; ++j) { float e = expf(row[j] - mx); row[j] = e; s += e; }
        float inv = 1.f / s;
        #pragma unroll
        for (int j = 0; j < 32; ++j) att[i][j] = row[j] * inv;
    }
    __syncthreads();

    const int o = tid;
    float wp[32];
    #pragma unroll
    for (int i2 = 0; i2 < 32; i2 += 4)
        *(float4*)&wp[i2] = *(const float4*)&Wproj[(size_t)o * DIM_ + h * 32 + i2];
    u16* arow = Amm + ((size_t)b * DIM_ + o) * DIM_ + h * 32;
    #pragma unroll
    for (int j = 0; j < 32; ++j) {
        float s = 0.f;
        #pragma unroll
        for (int i = 0; i < 32; ++i) s = fmaf(wp[i], att[i][j], s);
        arow[j] = f2bf(s);
    }
}

// ---------------------------------------------------------------------------
// cast Wfus [256][192] fp32 -> bf16 (once)
// ---------------------------------------------------------------------------
__global__ __launch_bounds__(256) void wfus_cast_kernel(
    const float* __restrict__ Wfus, u16* __restrict__ Afus)
{
    int idx = blockIdx.x * 256 + threadIdx.x;
    int base = idx * 8;
    float4 f0 = *(const float4*)(Wfus + base);
    float4 f1 = *(const float4*)(Wfus + base + 4);
    uint4 pk;
    pk.x = f2bf(f0.x) | ((u32)f2bf(f0.y) << 16);
    pk.y = f2bf(f0.z) | ((u32)f2bf(f0.w) << 16);
    pk.z = f2bf(f1.x) | ((u32)f2bf(f1.y) << 16);
    pk.w = f2bf(f1.z) | ((u32)f2bf(f1.w) << 16);
    *(uint4*)(Afus + base) = pk;
}

// ---------------------------------------------------------------------------
// final4 (R9-proven ~90us, FROZEN): 2 o-groups, 1-deep pipeline, age-ordered
// prefetch, __launch_bounds__(256,4). grid (128 px-panels, 2 o-groups, 8 b)
// ---------------------------------------------------------------------------
#define LOADB_F4(KC, W) do {                                                    \
    if ((KC) < 4) {                                                             \
        _Pragma("unroll") for (int i_ = 0; i_ < 2; ++i_) {                      \
            const u16* vb_ = vbuf + ((size_t)b * DIM_ + (KC) * 64 + (qq0 + 2 * i_) * 16) * HW_ + px0 + pxu; \
            _Pragma("unroll") for (int jj_ = 0; jj_ < 8; ++jj_)                 \
                W[i_][jj_] = (u32)vb_[(size_t)(2 * jj_) * HW_]                  \
                           | ((u32)vb_[(size_t)(2 * jj_ + 1) * HW_] << 16);     \
        }                                                                       \
    } else {                                                                    \
        const float* bp_ = ((KC) == 4) ? xin : ((KC) == 5) ? yin : zin;         \
        _Pragma("unroll") for (int i_ = 0; i_ < 2; ++i_) {                      \
            const float* sp_ = bp_ + ((size_t)b * CIN + (qq0 + 2 * i_) * 16) * HW_ + px0 + pxu; \
            _Pragma("unroll") for (int jj_ = 0; jj_ < 8; ++jj_)                 \
                W[i_][jj_] = (u32)f2bf(sp_[(size_t)(2 * jj_) * HW_])            \
                           | ((u32)f2bf(sp_[(size_t)(2 * jj_ + 1) * HW_]) << 16); \
        }                                                                       \
    } } while (0)

#define WRITEB_F4(BUF, W) do {                                                  \
    u16* dd_ = &Bl[BUF][pxu * 64];                                              \
    _Pragma("unroll") for (int i_ = 0; i_ < 2; ++i_) {                          \
        int qq_ = qq0 + 2 * i_;                                                 \
        *(uint4*)&dd_[(qq_ * 16)     ^ ((pxu & 7) << 3)] = make_uint4(W[i_][0], W[i_][1], W[i_][2], W[i_][3]); \
        *(uint4*)&dd_[(qq_ * 16 + 8) ^ ((pxu & 7) << 3)] = make_uint4(W[i_][4], W[i_][5], W[i_][6], W[i_][7]); \
    } } while (0)

#define LOADA_F4(KC, A) do {                                                    \
    _Pragma("unroll") for (int ks_ = 0; ks_ < 2; ++ks_)                         \
    _Pragma("unroll") for (int fm_ = 0; fm_ < 2; ++fm_) {                       \
        int m_ = m0 + fm_ * 16 + ln;                                            \
        const u16* ap_ = ((KC) < 4)                                             \
            ? Amm + ((size_t)b * DIM_ + m_) * DIM_ + (KC) * 64 + ks_ * 32 + g * 8 \
            : Afus + (size_t)m_ * 192 + ((KC) - 4) * 64 + ks_ * 32 + g * 8;     \
        A[ks_ * 2 + fm_] = *(const short8*)ap_;                                 \
    } } while (0)

__global__ __launch_bounds__(256, 4) void final4_kernel(
    const u16* __restrict__ Amm, const u16* __restrict__ Afus,
    const u16* __restrict__ vbuf,
    const float* __restrict__ xin, const float* __restrict__ yin,
    const float* __restrict__ zin, float* __restrict__ out)
{
    __shared__ u16 Bl[2][128 * 64];

    const int tid = threadIdx.x;
    const int px0 = blockIdx.x * 128;
    const int o0  = blockIdx.y * 128;
    const int b   = blockIdx.z;
    const int lane = tid & 63, wid = tid >> 6;
    const int g = lane >> 4, ln = lane & 15;
    const int m0 = o0 + wid * 32;
    const int pxu = tid & 127;
    const int qq0 = tid >> 7;      // 0 or 1

    f32x4 acc[2][8] = {};
    short8 aC[4], aN[4];
    u32 wN[2][8];

    LOADA_F4(0, aC);
    {
        u32 w0[2][8];
        LOADB_F4(0, w0);
        WRITEB_F4(0, w0);
    }
    __syncthreads();
    LOADA_F4(1, aN);
    LOADB_F4(1, wN);

    #pragma unroll
    for (int kc = 0; kc < 7; ++kc) {
        const int cur = kc & 1;

        #pragma unroll
        for (int ks = 0; ks < 2; ++ks)
            #pragma unroll
            for (int fn = 0; fn < 8; ++fn) {
                int p = fn * 16 + ln;
                short8 bf = *(const short8*)&Bl[cur][p * 64 + ((ks * 32 + g * 8) ^ ((p & 7) << 3))];
                acc[0][fn] = __builtin_amdgcn_mfma_f32_16x16x32_bf16(aC[ks * 2 + 0], bf, acc[0][fn], 0, 0, 0);
                acc[1][fn] = __builtin_amdgcn_mfma_f32_16x16x32_bf16(aC[ks * 2 + 1], bf, acc[1][fn], 0, 0, 0);
            }

        if (kc < 6) {
            WRITEB_F4(cur ^ 1, wN);
            __syncthreads();
            #pragma unroll
            for (int r = 0; r < 4; ++r) aC[r] = aN[r];
            if (kc < 5) {
                LOADA_F4(kc + 2, aN);
                LOADB_F4(kc + 2, wN);
            }
        }
    }

    float* op = out + (size_t)b * DIM_ * HW_;
    #pragma unroll
    for (int fm = 0; fm < 2; ++fm)
        #pragma unroll
        for (int fn = 0; fn < 8; ++fn)
            #pragma unroll
            for (int r = 0; r < 4; ++r) {
                int ch = m0 + fm * 16 + g * 4 + r;
                op[(size_t)ch * HW_ + px0 + fn * 16 + ln] = acc[fm][fn][r];
            }
}

// ---------------------------------------------------------------------------
extern "C" void kernel_launch(void* const* d_in, const int* in_sizes, int n_in,
                              void* d_out, int out_size, void* d_ws, size_t ws_size,
                              hipStream_t stream) {
    (void)in_sizes; (void)n_in; (void)out_size; (void)ws_size;

    const float* x     = (const float*)d_in[0];
    const float* y     = (const float*)d_in[1];
    const float* z     = (const float*)d_in[2];
    const float* Wq    = (const float*)d_in[3];
    const float* Wqd   = (const float*)d_in[4];
    const float* Wk    = (const float*)d_in[5];
    const float* Wkd   = (const float*)d_in[6];
    const float* Wv    = (const float*)d_in[7];
    const float* Wvd   = (const float*)d_in[8];
    const float* Wproj = (const float*)d_in[9];
    const float* Wfus  = (const float*)d_in[10];
    const float* temp  = (const float*)d_in[11];

    const size_t QELEMS = (size_t)B_ * DIM_ * HW_;   // 33.5M elems, 64 MiB bf16

    u16* qbuf = (u16*)d_out + QELEMS;         // q, dead after gram
    u16* kvbuf = (u16*)d_ws;                  // k, then v
    char* wsp = (char*)d_ws + QELEMS * sizeof(u16);
    float* pgram = (float*)wsp;                       wsp += 64 * 16 * 1024 * 4;
    float* pssq  = (float*)wsp;                       wsp += 64 * 16 * 32 * 4;
    float* pssk  = (float*)wsp;                       wsp += 64 * 16 * 32 * 4;
    u16*   Amm   = (u16*)wsp;                         wsp += (size_t)B_ * DIM_ * DIM_ * 2;
    u16*   Afus  = (u16*)wsp;

    wfus_cast_kernel<<<24, 256, 0, stream>>>(Wfus, Afus);
    // x->q and y->k fused into ONE launch (independent outputs)
    convdw_kernel<<<dim3(128, B_, 2), 512, 0, stream>>>(
        x, Wq, Wqd, qbuf, y, Wk, Wkd, kvbuf);
    gram_mfma_kernel<<<dim3(16, 64), 256, 0, stream>>>(qbuf, kvbuf, pgram, pssq, pssk);
    softproj_kernel<<<64, 256, 0, stream>>>(pgram, pssq, pssk, Wproj, temp, Amm);
    // z->v after gram (kvbuf WAR); same kernel, gridDim.z=1 uses set 0
    convdw_kernel<<<dim3(128, B_, 1), 512, 0, stream>>>(
        z, Wv, Wvd, kvbuf, z, Wv, Wvd, kvbuf);
    final4_kernel<<<dim3(128, 2, B_), 256, 0, stream>>>(Amm, Afus, kvbuf, x, y, z, (float*)d_out);
}